// Round 7
// baseline (178.556 us; speedup 1.0000x reference)
//
#include <hip/hip_runtime.h>

// Problem constants: B=8, C=3, T=16, H=W=224, P0=2, P=16, FC=2
#define Bd 8
#define Cd 3
#define Td 16
#define Hd 224
#define Wd 224
#define Nd 1568            // (T/2)*(H/16)*(W/16)
#define Dd 1024            // 2*16*16*2
#define HWd (Hd*Wd)        // 50176
#define MASK_N (Bd*Nd)     // 12544
#define PATCH_ELEMS 1536.0
#define GRID_MAIN 1024
#define BLK 256
#define STRIDE (GRID_MAIN*BLK)   // 262144

// ---------------- per-sample body: direct global bilinear gather ------------
// g indexes compacted sample space: slot = g>>9 (into list), s = g&511.
// Waves (64 lanes) never straddle a token: list load is wave-uniform,
// flow load is a fully-coalesced 512B float2 run.
__device__ __forceinline__ float body(int g,
                                      const float* __restrict__ outp,
                                      const float* __restrict__ raw,
                                      const int* __restrict__ list) {
    const int slot = g >> 9;
    const int s    = g & 511;
    const int tk   = list[slot];          // wave-uniform

    const int b   = tk / Nd;
    const int n   = tk - b * Nd;
    const int t2  = n / 196;
    const int rem = n - t2 * 196;
    const int ph  = rem / 14;
    const int pw  = rem - ph * 14;

    const int i0  = s >> 8;
    const int pix = s & 255;
    const int h = (ph << 4) + (pix >> 4);
    const int w = (pw << 4) + (pix & 15);
    const int t = (t2 << 1) + i0;

    float2 f = *(const float2*)(outp + ((size_t)tk << 10) + (s << 1));
    float mx = f.x + (float)w;
    float my = f.y + (float)h;

    float x0 = floorf(mx), y0 = floorf(my);
    float wx = mx - x0,    wy = my - y0;
    int x0i = (int)x0, y0i = (int)y0;
    int x1i = x0i + 1, y1i = y0i + 1;

    bool vx0 = (x0i >= 0) && (x0i < Wd);
    bool vx1 = (x1i >= 0) && (x1i < Wd);
    bool vy0 = (y0i >= 0) && (y0i < Hd);
    bool vy1 = (y1i >= 0) && (y1i < Hd);

    int xc0 = min(max(x0i, 0), Wd - 1);
    int xc1 = min(max(x1i, 0), Wd - 1);
    int yc0 = min(max(y0i, 0), Hd - 1);
    int yc1 = min(max(y1i, 0), Hd - 1);

    float w00 = (1.f - wx) * (1.f - wy) * ((vx0 && vy0) ? 1.f : 0.f);
    float w01 = wx         * (1.f - wy) * ((vx1 && vy0) ? 1.f : 0.f);
    float w10 = (1.f - wx) * wy         * ((vx0 && vy1) ? 1.f : 0.f);
    float w11 = wx         * wy         * ((vx1 && vy1) ? 1.f : 0.f);

    const int i00 = yc0 * Wd + xc0;
    const int i01 = yc0 * Wd + xc1;
    const int i10 = yc1 * Wd + xc0;
    const int i11 = yc1 * Wd + xc1;
    const int itg = h * Wd + w;

    const float* img0 = raw + (size_t)(b * 48 + t) * HWd;  // c=0 plane; +16*HWd per c
    float acc = 0.f;
    #pragma unroll
    for (int c = 0; c < Cd; ++c) {
        const float* img = img0 + c * (16 * HWd);
        float v00 = img[i00];
        float v01 = img[i01];
        float v10 = img[i10];
        float v11 = img[i11];
        float tgt = img[itg];
        float rec = v00 * w00 + v01 * w01 + v10 * w10 + v11 * w11;
        float d = rec - tgt;
        acc += d * d;
    }
    return acc;
}

// ---------------- compaction: single self-zeroing block ----------------
// 1024 threads, 13 strips of 1024; running prefix in registers (uniform).
__global__ void compact_kernel(const int* __restrict__ mask,
                               int* __restrict__ list,
                               unsigned int* __restrict__ cnt) {
    const int tid = threadIdx.x;
    __shared__ unsigned wt[16];
    unsigned base = 0;
    for (int i0 = 0; i0 < MASK_N; i0 += 1024) {
        int i = i0 + tid;
        bool m = (i < MASK_N) && (mask[i] != 0);
        unsigned long long bal = __ballot(m);
        int lane = tid & 63, wid = tid >> 6;
        unsigned pre  = (unsigned)__popcll(bal & ((1ull << lane) - 1ull));
        unsigned wtot = (unsigned)__popcll(bal);
        if (lane == 0) wt[wid] = wtot;
        __syncthreads();
        unsigned wbase = base;
        for (int k = 0; k < wid; ++k) wbase += wt[k];
        if (m) list[wbase + pre] = i;
        unsigned tot = 0;
        #pragma unroll
        for (int k = 0; k < 16; ++k) tot += wt[k];
        base += tot;
        __syncthreads();
    }
    if (tid == 0) *cnt = base;
}

// ---------------- main: compacted grid-stride gather, unroll-2 --------------
__global__ void flow_mse_gather(const float* __restrict__ outp,
                                const float* __restrict__ raw,
                                const int* __restrict__ list,
                                const unsigned int* __restrict__ cntp,
                                float* __restrict__ partial) {
    const int tid = threadIdx.x;
    const int total = (int)(*cntp) << 9;       // active samples

    float acc = 0.f;
    for (int g = blockIdx.x * BLK + tid; g < total; g += 2 * STRIDE) {
        acc += body(g, outp, raw, list);
        int g2 = g + STRIDE;
        // branch-free second body for ILP: clamp + discard if OOB
        float a2 = body(min(g2, total - 1), outp, raw, list);
        acc += (g2 < total) ? a2 : 0.f;
    }

    // block reduce: 4 waves of 64
    for (int off = 32; off > 0; off >>= 1) acc += __shfl_down(acc, off, 64);
    __shared__ float sdata[4];
    if ((tid & 63) == 0) sdata[tid >> 6] = acc;
    __syncthreads();
    if (tid == 0)
        partial[blockIdx.x] = sdata[0] + sdata[1] + sdata[2] + sdata[3];
}

// ---------------- finalize: reduce partials, denom from cnt ----------------
__global__ void finalize_kernel(const float* __restrict__ partial,
                                const unsigned int* __restrict__ cntp,
                                float* __restrict__ out) {
    double s = 0.0;
    for (int i = threadIdx.x; i < GRID_MAIN; i += blockDim.x)
        s += (double)partial[i];
    for (int off = 32; off > 0; off >>= 1)
        s += __shfl_down(s, off, 64);
    __shared__ double sdat[4];
    int lane = threadIdx.x & 63, wid = threadIdx.x >> 6;
    if (lane == 0) sdat[wid] = s;
    __syncthreads();
    if (threadIdx.x == 0) {
        double st = sdat[0] + sdat[1] + sdat[2] + sdat[3];
        unsigned ct = *cntp;
        double denom = (double)(ct > 0u ? ct : 1u) * PATCH_ELEMS;
        out[0] = (float)(st / denom);
    }
}

extern "C" void kernel_launch(void* const* d_in, const int* in_sizes, int n_in,
                              void* d_out, int out_size, void* d_ws, size_t ws_size,
                              hipStream_t stream) {
    const float* outp = (const float*)d_in[0];   // (B,N,D) fp32
    const float* raw  = (const float*)d_in[1];   // (B,C,T,H,W) fp32
    const int*   mask = (const int*)d_in[2];     // (B,N)
    float* out = (float*)d_out;

    // ws layout: [0,16) cnt | partial[GRID_MAIN] | list[MASK_N]
    unsigned int* cnt = (unsigned int*)d_ws;
    float* partial = (float*)((char*)d_ws + 16);
    int*   list    = (int*)((char*)d_ws + 16 + GRID_MAIN * 4);

    compact_kernel<<<1, 1024, 0, stream>>>(mask, list, cnt);
    flow_mse_gather<<<GRID_MAIN, BLK, 0, stream>>>(outp, raw, list, cnt, partial);
    finalize_kernel<<<1, 256, 0, stream>>>(partial, cnt, out);
}

// Round 8
// 171.200 us; speedup vs baseline: 1.0430x; 1.0430x over previous
//
#include <hip/hip_runtime.h>

// Problem constants: B=8, C=3, T=16, H=W=224, P0=2, P=16, FC=2
#define Bd 8
#define Cd 3
#define Td 16
#define Hd 224
#define Wd 224
#define Nd 1568            // (T/2)*(H/16)*(W/16)
#define Dd 1024            // 2*16*16*2
#define HWd (Hd*Wd)        // 50176
#define MASK_N (Bd*Nd)     // 12544
#define PATCH_ELEMS 1536.0

#define WINP 16            // window == patch: rows are 64B, 64B-aligned, 1 line/row
#define PLANE 256          // 16*16 floats
#define BUF (6*PLANE)      // 1536 floats = 6144 B per pipeline buffer
#define GRID_MAIN 2048
#define STG_V4 384         // 6 planes * 16 rows * 4 float4/row

struct TokGeo { int b, t2, ph, pw; };

__device__ __forceinline__ TokGeo geo(int tk) {
    TokGeo g;
    g.b = tk / Nd;
    int n = tk - g.b * Nd;
    g.t2 = n / 196;
    int rem = n - g.t2 * 196;
    g.ph = rem / 14;
    g.pw = rem - g.ph * 14;
    return g;
}

// staging index j -> global float-offset rel. to token window origin.
// LDS offset is simply j*4 floats (fully contiguous plane-major layout).
__device__ __forceinline__ int stg_goff(int j) {
    int p   = j >> 6;                  // plane = c*2 + i0  (64 float4 / plane)
    int rem = j & 63;
    int r   = rem >> 2;
    int c4  = (rem & 3) << 2;
    return (p >> 1) * (16 * HWd) + (p & 1) * HWd + r * Wd + c4;
}

__device__ __forceinline__ float compute_tok(const float* __restrict__ raw,
                                             const float* __restrict__ pl0,
                                             const TokGeo& g, int tid,
                                             float2 f0, float2 f1) {
    const int WX = g.pw << 4, WY = g.ph << 4;
    const int h = WY + (tid >> 4);
    const int w = WX + (tid & 15);
    float acc = 0.f;
    #pragma unroll
    for (int i0 = 0; i0 < 2; ++i0) {
        float2 f = i0 ? f1 : f0;
        float mx = f.x + (float)w;
        float my = f.y + (float)h;

        float x0 = floorf(mx), y0 = floorf(my);
        float wx = mx - x0,    wy = my - y0;
        int x0i = (int)x0, y0i = (int)y0;
        int x1i = x0i + 1, y1i = y0i + 1;

        bool vx0 = (x0i >= 0) && (x0i < Wd);
        bool vx1 = (x1i >= 0) && (x1i < Wd);
        bool vy0 = (y0i >= 0) && (y0i < Hd);
        bool vy1 = (y1i >= 0) && (y1i < Hd);

        int xc0 = min(max(x0i, 0), Wd - 1);
        int xc1 = min(max(x1i, 0), Wd - 1);
        int yc0 = min(max(y0i, 0), Hd - 1);
        int yc1 = min(max(y1i, 0), Hd - 1);

        float w00 = (1.f - wx) * (1.f - wy) * ((vx0 && vy0) ? 1.f : 0.f);
        float w01 = wx         * (1.f - wy) * ((vx1 && vy0) ? 1.f : 0.f);
        float w10 = (1.f - wx) * wy         * ((vx0 && vy1) ? 1.f : 0.f);
        float w11 = wx         * wy         * ((vx1 && vy1) ? 1.f : 0.f);

        const int lx0 = xc0 - WX, lx1 = xc1 - WX;
        const int ly0 = yc0 - WY, ly1 = yc1 - WY;
        const bool ok = (lx0 >= 0) & (lx1 < WINP) & (ly0 >= 0) & (ly1 < WINP);

        if (ok) {                       // all 4 corners inside the staged patch
            const int b00 = (ly0 << 4) + lx0;
            const int b01 = (ly0 << 4) + lx1;
            const int b10 = (ly1 << 4) + lx0;
            const int b11 = (ly1 << 4) + lx1;
            #pragma unroll
            for (int c = 0; c < Cd; ++c) {
                const float* pl = pl0 + ((c << 1) | i0) * PLANE;
                float rec = pl[b00] * w00 + pl[b01] * w01
                          + pl[b10] * w10 + pl[b11] * w11;
                float d = rec - pl[tid & 255];
                acc += d * d;
            }
        } else {                        // ~16% of samples: cross-patch gather
            const int i00 = yc0 * Wd + xc0;
            const int i01 = yc0 * Wd + xc1;
            const int i10 = yc1 * Wd + xc0;
            const int i11 = yc1 * Wd + xc1;
            const float* base = raw + (size_t)(g.b * 48 + (g.t2 << 1) + i0) * HWd;
            #pragma unroll
            for (int c = 0; c < Cd; ++c) {
                const float* img = base + c * (16 * HWd);
                float rec = img[i00] * w00 + img[i01] * w01
                          + img[i10] * w10 + img[i11] * w11;
                const float* pl = pl0 + ((c << 1) | i0) * PLANE;
                float d = rec - pl[tid & 255];
                acc += d * d;
            }
        }
    }
    return acc;
}

// ---------------- compaction: single self-zeroing block ----------------
__global__ void compact_kernel(const int* __restrict__ mask,
                               int* __restrict__ list,
                               unsigned int* __restrict__ cnt) {
    const int tid = threadIdx.x;
    __shared__ unsigned wt[16];
    unsigned base = 0;
    for (int i0 = 0; i0 < MASK_N; i0 += 1024) {
        int i = i0 + tid;
        bool m = (i < MASK_N) && (mask[i] != 0);
        unsigned long long bal = __ballot(m);
        int lane = tid & 63, wid = tid >> 6;
        unsigned pre  = (unsigned)__popcll(bal & ((1ull << lane) - 1ull));
        unsigned wtot = (unsigned)__popcll(bal);
        if (lane == 0) wt[wid] = wtot;
        __syncthreads();
        unsigned wbase = base;
        for (int k = 0; k < wid; ++k) wbase += wt[k];
        if (m) list[wbase + pre] = i;
        unsigned tot = 0;
        #pragma unroll
        for (int k = 0; k < 16; ++k) tot += wt[k];
        base += tot;
        __syncthreads();
    }
    if (tid == 0) *cnt = base;
}

// ---------------- main: persistent, double-buffered halo-free staging ------
__global__ __launch_bounds__(256, 6)
void flow_mse_main(const float* __restrict__ outp,
                   const float* __restrict__ raw,
                   const int* __restrict__ list,
                   const unsigned int* __restrict__ cntp,
                   float* __restrict__ partial) {
    __shared__ float lds[2 * BUF];        // 12288 B
    __shared__ float sdata[4];
    const int tid = threadIdx.x;
    const int cnt = (int)*cntp;

    // token-invariant staging geometry: k0 = all threads, k1 = tid<128
    const int q0 = stg_goff(tid);
    const bool k1 = tid < (STG_V4 - 256);
    const int q1 = stg_goff(k1 ? tid + 256 : 0);
    const int l0 = tid << 2;              // float offset in buffer
    const int l1 = (tid << 2) + 1024;

    float4 s0, s1;
    float2 fc0, fc1, fn0, fn1;
    TokGeo gc, gn;
    float acc = 0.f;

    int idx = blockIdx.x;
    int cur = 0;

    if (idx < cnt) {                      // prologue: stage first token
        int tk = list[idx];
        gc = geo(tk);
        const float* base = raw + (size_t)(gc.b * 48 + (gc.t2 << 1)) * HWd
                          + (gc.ph << 4) * Wd + (gc.pw << 4);
        s0 = *(const float4*)(base + q0);
        if (k1) s1 = *(const float4*)(base + q1);
        const float2* fp = (const float2*)(outp + ((size_t)tk << 10));
        fc0 = fp[tid]; fc1 = fp[256 + tid];
        *(float4*)(lds + l0) = s0;
        if (k1) *(float4*)(lds + l1) = s1;
    }

    while (idx < cnt) {                   // block-uniform condition
        int nidx = idx + GRID_MAIN;
        __syncthreads();                  // buffer `cur` staged & visible
        bool have_next = nidx < cnt;      // block-uniform
        if (have_next) {
            int ntk = list[nidx];
            gn = geo(ntk);
            const float* base = raw + (size_t)(gn.b * 48 + (gn.t2 << 1)) * HWd
                              + (gn.ph << 4) * Wd + (gn.pw << 4);
            s0 = *(const float4*)(base + q0);          // loads in flight...
            if (k1) s1 = *(const float4*)(base + q1);
            const float2* fp = (const float2*)(outp + ((size_t)ntk << 10));
            fn0 = fp[tid]; fn1 = fp[256 + tid];
        }
        acc += compute_tok(raw, lds + cur * BUF, gc, tid, fc0, fc1);  // ...during compute
        if (have_next) {
            float* dst = lds + (cur ^ 1) * BUF;
            *(float4*)(dst + l0) = s0;
            if (k1) *(float4*)(dst + l1) = s1;
        }
        idx = nidx; cur ^= 1;
        gc = gn; fc0 = fn0; fc1 = fn1;
    }

    // block reduce: 4 waves of 64
    for (int off = 32; off > 0; off >>= 1) acc += __shfl_down(acc, off, 64);
    if ((tid & 63) == 0) sdata[tid >> 6] = acc;
    __syncthreads();
    if (tid == 0)
        partial[blockIdx.x] = sdata[0] + sdata[1] + sdata[2] + sdata[3];
}

// ---------------- finalize: reduce partials, denom from cnt ----------------
__global__ void finalize_kernel(const float* __restrict__ partial,
                                const unsigned int* __restrict__ cntp,
                                float* __restrict__ out) {
    double s = 0.0;
    for (int i = threadIdx.x; i < GRID_MAIN; i += blockDim.x)
        s += (double)partial[i];
    for (int off = 32; off > 0; off >>= 1)
        s += __shfl_down(s, off, 64);
    __shared__ double sdat[4];
    int lane = threadIdx.x & 63, wid = threadIdx.x >> 6;
    if (lane == 0) sdat[wid] = s;
    __syncthreads();
    if (threadIdx.x == 0) {
        double st = sdat[0] + sdat[1] + sdat[2] + sdat[3];
        unsigned ct = *cntp;
        double denom = (double)(ct > 0u ? ct : 1u) * PATCH_ELEMS;
        out[0] = (float)(st / denom);
    }
}

extern "C" void kernel_launch(void* const* d_in, const int* in_sizes, int n_in,
                              void* d_out, int out_size, void* d_ws, size_t ws_size,
                              hipStream_t stream) {
    const float* outp = (const float*)d_in[0];   // (B,N,D) fp32
    const float* raw  = (const float*)d_in[1];   // (B,C,T,H,W) fp32
    const int*   mask = (const int*)d_in[2];     // (B,N)
    float* out = (float*)d_out;

    // ws layout: [0,16) cnt | partial[GRID_MAIN] | list[MASK_N]
    unsigned int* cnt = (unsigned int*)d_ws;
    float* partial = (float*)((char*)d_ws + 16);
    int*   list    = (int*)((char*)d_ws + 16 + GRID_MAIN * 4);

    compact_kernel<<<1, 1024, 0, stream>>>(mask, list, cnt);
    flow_mse_main<<<GRID_MAIN, 256, 0, stream>>>(outp, raw, list, cnt, partial);
    finalize_kernel<<<1, 256, 0, stream>>>(partial, cnt, out);
}

// Round 9
// 169.984 us; speedup vs baseline: 1.0504x; 1.0072x over previous
//
#include <hip/hip_runtime.h>

// Problem constants: B=8, C=3, T=16, H=W=224, P0=2, P=16, FC=2
#define Bd 8
#define Cd 3
#define Td 16
#define Hd 224
#define Wd 224
#define Nd 1568            // (T/2)*(H/16)*(W/16)
#define Dd 1024            // 2*16*16*2
#define HWd (Hd*Wd)        // 50176
#define MASK_N (Bd*Nd)     // 12544
#define PATCH_ELEMS 1536.0

#define WINP 16            // window == patch: rows are 64B, 64B-aligned
#define PLANE 256          // 16*16 floats
#define BUF (6*PLANE)      // 1536 floats = 6144 B per pipeline buffer
#define GRID_MAIN 1024
#define STG_V4 384         // 6 planes * 16 rows * 4 float4/row

struct TokGeo { int b, t2, ph, pw; };

__device__ __forceinline__ TokGeo geo(int tk) {
    TokGeo g;
    g.b = tk / Nd;
    int n = tk - g.b * Nd;
    g.t2 = n / 196;
    int rem = n - g.t2 * 196;
    g.ph = rem / 14;
    g.pw = rem - g.ph * 14;
    return g;
}

// staging index j -> global float-offset rel. to token window origin.
__device__ __forceinline__ int stg_goff(int j) {
    int p   = j >> 6;                  // plane = c*2 + i0
    int rem = j & 63;
    int r   = rem >> 2;
    int c4  = (rem & 3) << 2;
    return (p >> 1) * (16 * HWd) + (p & 1) * HWd + r * Wd + c4;
}

// ILP-restructured token compute: phase 1 issues ALL loads (LDS + predicated
// global fallback) into register arrays; phase 2 does the FMAs. Fully
// unrolled -> arrays live in VGPRs, ~26 loads outstanding per thread.
__device__ __forceinline__ float compute_tok(const float* __restrict__ raw,
                                             const float* __restrict__ pl0,
                                             const TokGeo& g, int tid,
                                             float2 f0, float2 f1) {
    const int WX = g.pw << 4, WY = g.ph << 4;
    const int h = WY + (tid >> 4);
    const int w = WX + (tid & 15);

    float v00[2][3], v01[2][3], v10[2][3], v11[2][3], tg[2][3];
    float W00[2], W01[2], W10[2], W11[2];

    // ---------------- load phase ----------------
    #pragma unroll
    for (int i0 = 0; i0 < 2; ++i0) {
        float2 f = i0 ? f1 : f0;
        float mx = f.x + (float)w;
        float my = f.y + (float)h;

        float x0 = floorf(mx), y0 = floorf(my);
        float wx = mx - x0,    wy = my - y0;
        int x0i = (int)x0, y0i = (int)y0;
        int x1i = x0i + 1, y1i = y0i + 1;

        bool vx0 = (x0i >= 0) && (x0i < Wd);
        bool vx1 = (x1i >= 0) && (x1i < Wd);
        bool vy0 = (y0i >= 0) && (y0i < Hd);
        bool vy1 = (y1i >= 0) && (y1i < Hd);

        int xc0 = min(max(x0i, 0), Wd - 1);
        int xc1 = min(max(x1i, 0), Wd - 1);
        int yc0 = min(max(y0i, 0), Hd - 1);
        int yc1 = min(max(y1i, 0), Hd - 1);

        W00[i0] = (1.f - wx) * (1.f - wy) * ((vx0 && vy0) ? 1.f : 0.f);
        W01[i0] = wx         * (1.f - wy) * ((vx1 && vy0) ? 1.f : 0.f);
        W10[i0] = (1.f - wx) * wy         * ((vx0 && vy1) ? 1.f : 0.f);
        W11[i0] = wx         * wy         * ((vx1 && vy1) ? 1.f : 0.f);

        const int lx0 = xc0 - WX, lx1 = xc1 - WX;
        const int ly0 = yc0 - WY, ly1 = yc1 - WY;
        const bool ok = (lx0 >= 0) & (lx1 < WINP) & (ly0 >= 0) & (ly1 < WINP);

        #pragma unroll
        for (int c = 0; c < Cd; ++c)     // target always staged
            tg[i0][c] = pl0[(((c << 1) | i0) * PLANE) + tid];

        if (ok) {
            const int b00 = (ly0 << 4) + lx0;
            const int b01 = (ly0 << 4) + lx1;
            const int b10 = (ly1 << 4) + lx0;
            const int b11 = (ly1 << 4) + lx1;
            #pragma unroll
            for (int c = 0; c < Cd; ++c) {
                const float* pl = pl0 + ((c << 1) | i0) * PLANE;
                v00[i0][c] = pl[b00];
                v01[i0][c] = pl[b01];
                v10[i0][c] = pl[b10];
                v11[i0][c] = pl[b11];
            }
        } else {                          // cross-patch: global gather
            const int i00 = yc0 * Wd + xc0;
            const int i01 = yc0 * Wd + xc1;
            const int i10 = yc1 * Wd + xc0;
            const int i11 = yc1 * Wd + xc1;
            const float* base = raw + (size_t)(g.b * 48 + (g.t2 << 1) + i0) * HWd;
            #pragma unroll
            for (int c = 0; c < Cd; ++c) {
                const float* img = base + c * (16 * HWd);
                v00[i0][c] = img[i00];
                v01[i0][c] = img[i01];
                v10[i0][c] = img[i10];
                v11[i0][c] = img[i11];
            }
        }
    }

    // ---------------- compute phase ----------------
    float acc = 0.f;
    #pragma unroll
    for (int i0 = 0; i0 < 2; ++i0) {
        #pragma unroll
        for (int c = 0; c < Cd; ++c) {
            float rec = v00[i0][c] * W00[i0] + v01[i0][c] * W01[i0]
                      + v10[i0][c] * W10[i0] + v11[i0][c] * W11[i0];
            float d = rec - tg[i0][c];
            acc += d * d;
        }
    }
    return acc;
}

// ---------------- compaction: single self-zeroing block ----------------
__global__ void compact_kernel(const int* __restrict__ mask,
                               int* __restrict__ list,
                               unsigned int* __restrict__ cnt) {
    const int tid = threadIdx.x;
    __shared__ unsigned wt[16];
    unsigned base = 0;
    for (int i0 = 0; i0 < MASK_N; i0 += 1024) {
        int i = i0 + tid;
        bool m = (i < MASK_N) && (mask[i] != 0);
        unsigned long long bal = __ballot(m);
        int lane = tid & 63, wid = tid >> 6;
        unsigned pre  = (unsigned)__popcll(bal & ((1ull << lane) - 1ull));
        unsigned wtot = (unsigned)__popcll(bal);
        if (lane == 0) wt[wid] = wtot;
        __syncthreads();
        unsigned wbase = base;
        for (int k = 0; k < wid; ++k) wbase += wt[k];
        if (m) list[wbase + pre] = i;
        unsigned tot = 0;
        #pragma unroll
        for (int k = 0; k < 16; ++k) tot += wt[k];
        base += tot;
        __syncthreads();
    }
    if (tid == 0) *cnt = base;
}

// ---------------- main: persistent, double-buffered halo-free staging ------
__global__ __launch_bounds__(256)
void flow_mse_main(const float* __restrict__ outp,
                   const float* __restrict__ raw,
                   const int* __restrict__ list,
                   const unsigned int* __restrict__ cntp,
                   float* __restrict__ partial) {
    __shared__ float lds[2 * BUF];        // 12288 B
    __shared__ float sdata[4];
    const int tid = threadIdx.x;
    const int cnt = (int)*cntp;

    // token-invariant staging geometry: k0 = all threads, k1 = tid<128
    const int q0 = stg_goff(tid);
    const bool k1 = tid < (STG_V4 - 256);
    const int q1 = stg_goff(k1 ? tid + 256 : 0);
    const int l0 = tid << 2;
    const int l1 = (tid << 2) + 1024;

    float4 s0, s1;
    float2 fc0, fc1, fn0, fn1;
    TokGeo gc, gn;
    float acc = 0.f;

    int idx = blockIdx.x;
    int cur = 0;

    if (idx < cnt) {                      // prologue: stage first token
        int tk = list[idx];
        gc = geo(tk);
        const float* base = raw + (size_t)(gc.b * 48 + (gc.t2 << 1)) * HWd
                          + (gc.ph << 4) * Wd + (gc.pw << 4);
        s0 = *(const float4*)(base + q0);
        if (k1) s1 = *(const float4*)(base + q1);
        const float2* fp = (const float2*)(outp + ((size_t)tk << 10));
        fc0 = fp[tid]; fc1 = fp[256 + tid];
        *(float4*)(lds + l0) = s0;
        if (k1) *(float4*)(lds + l1) = s1;
    }

    while (idx < cnt) {                   // block-uniform condition
        int nidx = idx + GRID_MAIN;
        __syncthreads();                  // buffer `cur` staged & visible
        bool have_next = nidx < cnt;      // block-uniform
        if (have_next) {
            int ntk = list[nidx];
            gn = geo(ntk);
            const float* base = raw + (size_t)(gn.b * 48 + (gn.t2 << 1)) * HWd
                              + (gn.ph << 4) * Wd + (gn.pw << 4);
            s0 = *(const float4*)(base + q0);          // loads in flight...
            if (k1) s1 = *(const float4*)(base + q1);
            const float2* fp = (const float2*)(outp + ((size_t)ntk << 10));
            fn0 = fp[tid]; fn1 = fp[256 + tid];
        }
        acc += compute_tok(raw, lds + cur * BUF, gc, tid, fc0, fc1);  // ...during compute
        if (have_next) {
            float* dst = lds + (cur ^ 1) * BUF;
            *(float4*)(dst + l0) = s0;
            if (k1) *(float4*)(dst + l1) = s1;
        }
        idx = nidx; cur ^= 1;
        gc = gn; fc0 = fn0; fc1 = fn1;
    }

    // block reduce: 4 waves of 64
    for (int off = 32; off > 0; off >>= 1) acc += __shfl_down(acc, off, 64);
    if ((tid & 63) == 0) sdata[tid >> 6] = acc;
    __syncthreads();
    if (tid == 0)
        partial[blockIdx.x] = sdata[0] + sdata[1] + sdata[2] + sdata[3];
}

// ---------------- finalize: reduce partials, denom from cnt ----------------
__global__ void finalize_kernel(const float* __restrict__ partial,
                                const unsigned int* __restrict__ cntp,
                                float* __restrict__ out) {
    double s = 0.0;
    for (int i = threadIdx.x; i < GRID_MAIN; i += blockDim.x)
        s += (double)partial[i];
    for (int off = 32; off > 0; off >>= 1)
        s += __shfl_down(s, off, 64);
    __shared__ double sdat[4];
    int lane = threadIdx.x & 63, wid = threadIdx.x >> 6;
    if (lane == 0) sdat[wid] = s;
    __syncthreads();
    if (threadIdx.x == 0) {
        double st = sdat[0] + sdat[1] + sdat[2] + sdat[3];
        unsigned ct = *cntp;
        double denom = (double)(ct > 0u ? ct : 1u) * PATCH_ELEMS;
        out[0] = (float)(st / denom);
    }
}

extern "C" void kernel_launch(void* const* d_in, const int* in_sizes, int n_in,
                              void* d_out, int out_size, void* d_ws, size_t ws_size,
                              hipStream_t stream) {
    const float* outp = (const float*)d_in[0];   // (B,N,D) fp32
    const float* raw  = (const float*)d_in[1];   // (B,C,T,H,W) fp32
    const int*   mask = (const int*)d_in[2];     // (B,N)
    float* out = (float*)d_out;

    // ws layout: [0,16) cnt | partial[GRID_MAIN] | list[MASK_N]
    unsigned int* cnt = (unsigned int*)d_ws;
    float* partial = (float*)((char*)d_ws + 16);
    int*   list    = (int*)((char*)d_ws + 16 + GRID_MAIN * 4);

    compact_kernel<<<1, 1024, 0, stream>>>(mask, list, cnt);
    flow_mse_main<<<GRID_MAIN, 256, 0, stream>>>(outp, raw, list, cnt, partial);
    finalize_kernel<<<1, 256, 0, stream>>>(partial, cnt, out);
}

// Round 10
// 155.620 us; speedup vs baseline: 1.1474x; 1.0923x over previous
//
#include <hip/hip_runtime.h>

// Problem constants: B=8, C=3, T=16, H=W=224, P0=2, P=16, FC=2
#define Bd 8
#define Cd 3
#define Td 16
#define Hd 224
#define Wd 224
#define Nd 1568            // (T/2)*(H/16)*(W/16)
#define Dd 1024            // 2*16*16*2
#define HWd (Hd*Wd)        // 50176
#define MASK_N (Bd*Nd)     // 12544
#define PATCH_ELEMS 1536.0

#define WINP 16            // window == patch: rows are 64B, 64B-aligned
#define PLANE 256          // 16*16 floats
#define BUF (6*PLANE)      // 1536 floats = 6144 B per pipeline buffer
#define GRID_MAIN 1024
#define STG_V4 384         // 6 planes * 16 rows * 4 float4/row
#define NSEG 13            // compaction segments of 1024 mask entries

struct TokGeo { int b, t2, ph, pw; };

__device__ __forceinline__ TokGeo geo(int tk) {
    TokGeo g;
    g.b = tk / Nd;
    int n = tk - g.b * Nd;
    g.t2 = n / 196;
    int rem = n - g.t2 * 196;
    g.ph = rem / 14;
    g.pw = rem - g.ph * 14;
    return g;
}

__device__ __forceinline__ int stg_goff(int j) {
    int p   = j >> 6;                  // plane = c*2 + i0
    int rem = j & 63;
    int r   = rem >> 2;
    int c4  = (rem & 3) << 2;
    return (p >> 1) * (16 * HWd) + (p & 1) * HWd + r * Wd + c4;
}

// ILP token compute: phase 1 issues ALL loads into register arrays,
// phase 2 does the FMAs (R9 body, unchanged).
__device__ __forceinline__ float compute_tok(const float* __restrict__ raw,
                                             const float* __restrict__ pl0,
                                             const TokGeo& g, int tid,
                                             float2 f0, float2 f1) {
    const int WX = g.pw << 4, WY = g.ph << 4;
    const int h = WY + (tid >> 4);
    const int w = WX + (tid & 15);

    float v00[2][3], v01[2][3], v10[2][3], v11[2][3], tg[2][3];
    float W00[2], W01[2], W10[2], W11[2];

    #pragma unroll
    for (int i0 = 0; i0 < 2; ++i0) {
        float2 f = i0 ? f1 : f0;
        float mx = f.x + (float)w;
        float my = f.y + (float)h;

        float x0 = floorf(mx), y0 = floorf(my);
        float wx = mx - x0,    wy = my - y0;
        int x0i = (int)x0, y0i = (int)y0;
        int x1i = x0i + 1, y1i = y0i + 1;

        bool vx0 = (x0i >= 0) && (x0i < Wd);
        bool vx1 = (x1i >= 0) && (x1i < Wd);
        bool vy0 = (y0i >= 0) && (y0i < Hd);
        bool vy1 = (y1i >= 0) && (y1i < Hd);

        int xc0 = min(max(x0i, 0), Wd - 1);
        int xc1 = min(max(x1i, 0), Wd - 1);
        int yc0 = min(max(y0i, 0), Hd - 1);
        int yc1 = min(max(y1i, 0), Hd - 1);

        W00[i0] = (1.f - wx) * (1.f - wy) * ((vx0 && vy0) ? 1.f : 0.f);
        W01[i0] = wx         * (1.f - wy) * ((vx1 && vy0) ? 1.f : 0.f);
        W10[i0] = (1.f - wx) * wy         * ((vx0 && vy1) ? 1.f : 0.f);
        W11[i0] = wx         * wy         * ((vx1 && vy1) ? 1.f : 0.f);

        const int lx0 = xc0 - WX, lx1 = xc1 - WX;
        const int ly0 = yc0 - WY, ly1 = yc1 - WY;
        const bool ok = (lx0 >= 0) & (lx1 < WINP) & (ly0 >= 0) & (ly1 < WINP);

        #pragma unroll
        for (int c = 0; c < Cd; ++c)
            tg[i0][c] = pl0[(((c << 1) | i0) * PLANE) + tid];

        if (ok) {
            const int b00 = (ly0 << 4) + lx0;
            const int b01 = (ly0 << 4) + lx1;
            const int b10 = (ly1 << 4) + lx0;
            const int b11 = (ly1 << 4) + lx1;
            #pragma unroll
            for (int c = 0; c < Cd; ++c) {
                const float* pl = pl0 + ((c << 1) | i0) * PLANE;
                v00[i0][c] = pl[b00];
                v01[i0][c] = pl[b01];
                v10[i0][c] = pl[b10];
                v11[i0][c] = pl[b11];
            }
        } else {
            const int i00 = yc0 * Wd + xc0;
            const int i01 = yc0 * Wd + xc1;
            const int i10 = yc1 * Wd + xc0;
            const int i11 = yc1 * Wd + xc1;
            const float* base = raw + (size_t)(g.b * 48 + (g.t2 << 1) + i0) * HWd;
            #pragma unroll
            for (int c = 0; c < Cd; ++c) {
                const float* img = base + c * (16 * HWd);
                v00[i0][c] = img[i00];
                v01[i0][c] = img[i01];
                v10[i0][c] = img[i10];
                v11[i0][c] = img[i11];
            }
        }
    }

    float acc = 0.f;
    #pragma unroll
    for (int i0 = 0; i0 < 2; ++i0) {
        #pragma unroll
        for (int c = 0; c < Cd; ++c) {
            float rec = v00[i0][c] * W00[i0] + v01[i0][c] * W01[i0]
                      + v10[i0][c] * W10[i0] + v11[i0][c] * W11[i0];
            float d = rec - tg[i0][c];
            acc += d * d;
        }
    }
    return acc;
}

// ---------------- compaction: 13 parallel segmented blocks -----------------
// Block j compacts mask[j*1024 .. ) into list[j*1024 ..] and writes bcnt[j].
// No atomics, no zero-init needed, single strip -> ~2 us.
__global__ void compact_kernel(const int* __restrict__ mask,
                               int* __restrict__ list,
                               int* __restrict__ bcnt) {
    const int j   = blockIdx.x;
    const int tid = threadIdx.x;
    const int i   = (j << 10) + tid;
    bool m = (i < MASK_N) && (mask[i] != 0);
    unsigned long long bal = __ballot(m);
    int lane = tid & 63, wid = tid >> 6;          // wid 0..15
    __shared__ unsigned wt[16];
    unsigned pre = (unsigned)__popcll(bal & ((1ull << lane) - 1ull));
    if (lane == 0) wt[wid] = (unsigned)__popcll(bal);
    __syncthreads();
    unsigned base = 0;
    for (int k = 0; k < wid; ++k) base += wt[k];
    if (m) list[(j << 10) + base + pre] = i;
    if (tid == 0) {
        unsigned tot = 0;
        #pragma unroll
        for (int k = 0; k < 16; ++k) tot += wt[k];
        bcnt[j] = (int)tot;
    }
}

// ---------------- main: persistent, double-buffered halo-free staging ------
__global__ __launch_bounds__(256)
void flow_mse_main(const float* __restrict__ outp,
                   const float* __restrict__ raw,
                   const int* __restrict__ list,
                   const int* __restrict__ bcnt,
                   float* __restrict__ partial) {
    __shared__ float lds[2 * BUF];        // 12288 B
    __shared__ float sdata[4];
    const int tid = threadIdx.x;

    // register prefix over the 13 segment counts (wave-uniform scalar loads)
    int pre1  = bcnt[0];
    int pre2  = pre1  + bcnt[1];
    int pre3  = pre2  + bcnt[2];
    int pre4  = pre3  + bcnt[3];
    int pre5  = pre4  + bcnt[4];
    int pre6  = pre5  + bcnt[5];
    int pre7  = pre6  + bcnt[6];
    int pre8  = pre7  + bcnt[7];
    int pre9  = pre8  + bcnt[8];
    int pre10 = pre9  + bcnt[9];
    int pre11 = pre10 + bcnt[10];
    int pre12 = pre11 + bcnt[11];
    const int cnt = pre12 + bcnt[12];

    // slot -> token: unrolled select chain over the prefix (no dyn indexing)
    #define SLOT2TK(slot, tk_out) do {                                   \
        int _s = (slot);                                                 \
        int _seg = 0, _base = 0;                                         \
        if (_s >= pre1)  { _seg = 1;  _base = pre1;  }                   \
        if (_s >= pre2)  { _seg = 2;  _base = pre2;  }                   \
        if (_s >= pre3)  { _seg = 3;  _base = pre3;  }                   \
        if (_s >= pre4)  { _seg = 4;  _base = pre4;  }                   \
        if (_s >= pre5)  { _seg = 5;  _base = pre5;  }                   \
        if (_s >= pre6)  { _seg = 6;  _base = pre6;  }                   \
        if (_s >= pre7)  { _seg = 7;  _base = pre7;  }                   \
        if (_s >= pre8)  { _seg = 8;  _base = pre8;  }                   \
        if (_s >= pre9)  { _seg = 9;  _base = pre9;  }                   \
        if (_s >= pre10) { _seg = 10; _base = pre10; }                   \
        if (_s >= pre11) { _seg = 11; _base = pre11; }                   \
        if (_s >= pre12) { _seg = 12; _base = pre12; }                   \
        (tk_out) = list[(_seg << 10) + _s - _base];                      \
    } while (0)

    const int q0 = stg_goff(tid);
    const bool k1 = tid < (STG_V4 - 256);
    const int q1 = stg_goff(k1 ? tid + 256 : 0);
    const int l0 = tid << 2;
    const int l1 = (tid << 2) + 1024;

    float4 s0, s1;
    float2 fc0, fc1, fn0, fn1;
    TokGeo gc, gn;
    float acc = 0.f;

    int idx = blockIdx.x;
    int cur = 0;

    if (idx < cnt) {                      // prologue: stage first token
        int tk; SLOT2TK(idx, tk);
        gc = geo(tk);
        const float* base = raw + (size_t)(gc.b * 48 + (gc.t2 << 1)) * HWd
                          + (gc.ph << 4) * Wd + (gc.pw << 4);
        s0 = *(const float4*)(base + q0);
        if (k1) s1 = *(const float4*)(base + q1);
        const float2* fp = (const float2*)(outp + ((size_t)tk << 10));
        fc0 = fp[tid]; fc1 = fp[256 + tid];
        *(float4*)(lds + l0) = s0;
        if (k1) *(float4*)(lds + l1) = s1;
    }

    while (idx < cnt) {                   // block-uniform condition
        int nidx = idx + GRID_MAIN;
        __syncthreads();                  // buffer `cur` staged & visible
        bool have_next = nidx < cnt;      // block-uniform
        if (have_next) {
            int ntk; SLOT2TK(nidx, ntk);
            gn = geo(ntk);
            const float* base = raw + (size_t)(gn.b * 48 + (gn.t2 << 1)) * HWd
                              + (gn.ph << 4) * Wd + (gn.pw << 4);
            s0 = *(const float4*)(base + q0);          // loads in flight...
            if (k1) s1 = *(const float4*)(base + q1);
            const float2* fp = (const float2*)(outp + ((size_t)ntk << 10));
            fn0 = fp[tid]; fn1 = fp[256 + tid];
        }
        acc += compute_tok(raw, lds + cur * BUF, gc, tid, fc0, fc1);  // ...during compute
        if (have_next) {
            float* dst = lds + (cur ^ 1) * BUF;
            *(float4*)(dst + l0) = s0;
            if (k1) *(float4*)(dst + l1) = s1;
        }
        idx = nidx; cur ^= 1;
        gc = gn; fc0 = fn0; fc1 = fn1;
    }

    // block reduce: 4 waves of 64
    for (int off = 32; off > 0; off >>= 1) acc += __shfl_down(acc, off, 64);
    if ((tid & 63) == 0) sdata[tid >> 6] = acc;
    __syncthreads();
    if (tid == 0)
        partial[blockIdx.x] = sdata[0] + sdata[1] + sdata[2] + sdata[3];
    #undef SLOT2TK
}

// ---------------- finalize: reduce partials, denom from bcnt ---------------
__global__ void finalize_kernel(const float* __restrict__ partial,
                                const int* __restrict__ bcnt,
                                float* __restrict__ out) {
    double s = 0.0;
    for (int i = threadIdx.x; i < GRID_MAIN; i += blockDim.x)
        s += (double)partial[i];
    for (int off = 32; off > 0; off >>= 1)
        s += __shfl_down(s, off, 64);
    __shared__ double sdat[4];
    int lane = threadIdx.x & 63, wid = threadIdx.x >> 6;
    if (lane == 0) sdat[wid] = s;
    __syncthreads();
    if (threadIdx.x == 0) {
        double st = sdat[0] + sdat[1] + sdat[2] + sdat[3];
        int ct = 0;
        #pragma unroll
        for (int k = 0; k < NSEG; ++k) ct += bcnt[k];
        double denom = (double)(ct > 0 ? ct : 1) * PATCH_ELEMS;
        out[0] = (float)(st / denom);
    }
}

extern "C" void kernel_launch(void* const* d_in, const int* in_sizes, int n_in,
                              void* d_out, int out_size, void* d_ws, size_t ws_size,
                              hipStream_t stream) {
    const float* outp = (const float*)d_in[0];   // (B,N,D) fp32
    const float* raw  = (const float*)d_in[1];   // (B,C,T,H,W) fp32
    const int*   mask = (const int*)d_in[2];     // (B,N)
    float* out = (float*)d_out;

    // ws layout: bcnt[16] | partial[GRID_MAIN] | list[NSEG*1024]
    int*   bcnt    = (int*)d_ws;
    float* partial = (float*)((char*)d_ws + 64);
    int*   list    = (int*)((char*)d_ws + 64 + GRID_MAIN * 4);

    compact_kernel<<<NSEG, 1024, 0, stream>>>(mask, list, bcnt);
    flow_mse_main<<<GRID_MAIN, 256, 0, stream>>>(outp, raw, list, bcnt, partial);
    finalize_kernel<<<1, 256, 0, stream>>>(partial, bcnt, out);
}